// Round 1
// 124.020 us; speedup vs baseline: 1.0376x; 1.0376x over previous
//
#include <hip/hip_runtime.h>

typedef _Float16 half_t;
typedef __attribute__((ext_vector_type(8))) _Float16 half8;
typedef __attribute__((ext_vector_type(4))) _Float16 half4;
typedef __attribute__((ext_vector_type(4))) float floatx4;
typedef __attribute__((ext_vector_type(16))) float floatx16;

#define MFMA16(A, B, C) __builtin_amdgcn_mfma_f32_16x16x32_f16((A), (B), (C), 0, 0, 0)
#define MFMA32(A, B, C) __builtin_amdgcn_mfma_f32_32x32x16_f16((A), (B), (C), 0, 0, 0)

// ----------------------------------------------------------------- k_qkv ----
// Per (t-tile tx, window w): qkv = Xw(128x64) @ W^T(64x192) + bias.
// v2: epilogue stages the 128x192 half outputs in LDS (union with Xs/Ws,
// dead after the MFMA loop) and emits fully-coalesced half8 stores:
// q,k rows give 512B-contiguous wave segments, vT rows 256B segments.
__global__ __launch_bounds__(256) void k_qkv(
    const float* __restrict__ x, const float* __restrict__ W,
    const float* __restrict__ bias, half_t* __restrict__ q,
    half_t* __restrict__ k, half_t* __restrict__ vT,
    float* __restrict__ qp, float* __restrict__ kp) {
  // union: [Xs 128x72 | Ws 192x72] (46080B)  vs  [S1 128x136 | S2 64x136] (52224B)
  __shared__ __align__(16) char smem[52736];
  half_t(*Xs)[72] = (half_t(*)[72])smem;              // 18432B
  half_t(*Ws)[72] = (half_t(*)[72])(smem + 18432);    // 27648B
  half_t(*S1)[136] = (half_t(*)[136])smem;            // 34816B (q|k cols 0..127)
  half_t(*S2)[136] = (half_t(*)[136])(smem + 34816);  // 17408B (v, [oc][t])
  float* qs_l = (float*)(smem + 52224);
  float* ks_l = qs_l + 64;
  const int w = blockIdx.y;
  const int tx = blockIdx.x;
  const int t0 = tx * 128;
  const int ih = w >> 3, iw = w & 7;
  const int xbase = ih * 8192 + iw * 32;
  const int tid = threadIdx.x;

  for (int i = tid; i < 8192; i += 256) {
    const int c = i >> 7, tt = i & 127;
    const int t = t0 + tt;
    Xs[tt][c] = (half_t)x[c * 65536 + xbase + (t >> 5) * 256 + (t & 31)];
  }
  for (int i = tid; i < 3072; i += 256) {
    const int o = i >> 4, c4 = (i & 15) * 4;
    const floatx4 v = *(const floatx4*)&W[o * 64 + c4];
    half4 hv;
    #pragma unroll
    for (int p = 0; p < 4; p++) hv[p] = (half_t)v[p];
    *(half4*)&Ws[o][c4] = hv;
  }
  if (tid < 64) { qs_l[tid] = 0.f; ks_l[tid] = 0.f; }
  __syncthreads();

  const int wave = tid >> 6, lane = tid & 63;
  const int lrow = lane & 15, lq = lane >> 4;
  const int rbase = (wave >> 1) * 64;
  const int cbase = (wave & 1) * 96;

  floatx4 acc[4][6];
  const floatx4 z = {0.f, 0.f, 0.f, 0.f};
  #pragma unroll
  for (int mt = 0; mt < 4; mt++)
    #pragma unroll
    for (int nt = 0; nt < 6; nt++) acc[mt][nt] = z;

  #pragma unroll
  for (int kf = 0; kf < 2; kf++) {
    const int koff = kf * 32 + lq * 8;
    half8 a[4], b[6];
    #pragma unroll
    for (int mt = 0; mt < 4; mt++)
      a[mt] = *(const half8*)&Xs[rbase + mt * 16 + lrow][koff];
    #pragma unroll
    for (int nt = 0; nt < 6; nt++)
      b[nt] = *(const half8*)&Ws[cbase + nt * 16 + lrow][koff];
    #pragma unroll
    for (int mt = 0; mt < 4; mt++)
      #pragma unroll
      for (int nt = 0; nt < 6; nt++)
        acc[mt][nt] = MFMA16(a[mt], b[nt], acc[mt][nt]);
  }
  __syncthreads();  // Xs/Ws dead; smem becomes S1/S2

  #pragma unroll
  for (int nt = 0; nt < 6; nt++) {
    const int o = cbase + nt * 16 + lrow;
    const float bs = bias[o];
    if (o < 128) {  // q (o<64) or k (64<=o<128): stage rows [t][o]
      float s = 0.f;
      #pragma unroll
      for (int mt = 0; mt < 4; mt++) {
        const int tr = rbase + mt * 16 + lq * 4;
        #pragma unroll
        for (int r = 0; r < 4; r++) {
          const float v = acc[mt][nt][r] + bs;
          S1[tr + r][o] = (half_t)v;
          s += v;
        }
      }
      if (o < 64) atomicAdd(&qs_l[o], s);
      else atomicAdd(&ks_l[o - 64], s);
    } else {  // v: stage transposed [oc][t] as packed half4
      const int oc = o - 128;
      #pragma unroll
      for (int mt = 0; mt < 4; mt++) {
        const int tr = rbase + mt * 16 + lq * 4;
        half4 pk;
        #pragma unroll
        for (int r = 0; r < 4; r++) pk[r] = (half_t)(acc[mt][nt][r] + bs);
        *(half4*)&S2[oc][tr] = pk;
      }
    }
  }
  __syncthreads();

  // coalesced wide stores: q,k 2048 half8 (wave = 4 t-rows x 1KB), vT 1024
  for (int idx = tid; idx < 3072; idx += 256) {
    if (idx < 2048) {
      const int t = idx >> 4, seg = idx & 15;
      const half8 v = *(const half8*)&S1[t][seg * 8];
      if (seg < 8)
        *(half8*)&q[w * 65536 + (t0 + t) * 64 + seg * 8] = v;
      else
        *(half8*)&k[w * 65536 + (t0 + t) * 64 + (seg - 8) * 8] = v;
    } else {
      const int i2 = idx - 2048;
      const int oc = i2 >> 4, seg = i2 & 15;
      *(half8*)&vT[w * 65536 + oc * 1024 + t0 + seg * 8] =
          *(const half8*)&S2[oc][seg * 8];
    }
  }
  if (tid < 64) {
    qp[(w * 8 + tx) * 64 + tid] = qs_l[tid];
    kp[(w * 8 + tx) * 64 + tid] = ks_l[tid];
  }
}

// ----------------------------------------------------------------- k_mix ----
// v2: k_ar folded in. Prologue: (1) issue t32=0 B-frag global loads (stay in
// flight), (2) reduce qp/kp -> fp16 qsum/ksum in LDS, (3) ar = relu(qs.ks^T)
// * 2^-20 via 8x MFMA16 (fp32 accum), relu'd into arL LDS. Main GEMM:
// D[i][pos] = sum_j ar[i][j] * src[j][pos], M=64, K=64, N=65536.
__global__ __launch_bounds__(256) void k_mix(const half_t* __restrict__ q,
                                             const half_t* __restrict__ k,
                                             const float* __restrict__ qp,
                                             const float* __restrict__ kp,
                                             half_t* __restrict__ qm,
                                             half_t* __restrict__ km) {
  __shared__ __align__(16) half_t qh[64][72];
  __shared__ __align__(16) half_t kh[64][72];
  __shared__ __align__(16) half_t arL[64][72];
  const half_t* __restrict__ src = blockIdx.y ? k : q;
  half_t* __restrict__ dst = blockIdx.y ? km : qm;
  const int tid = threadIdx.x;
  const int wave = tid >> 6, lane = tid & 63;
  const int ln31 = lane & 31;
  const int hk8 = (lane >> 5) * 8;
  const int lrow = lane & 15, lq = lane >> 4;

  // (1) t32=0 B-frags issued first: HBM latency hides under the prologue
  const int pos0 = blockIdx.x * 256 + wave * 64 + ln31;
  half8 bB0[4];
  #pragma unroll
  for (int kk = 0; kk < 4; kk++)
    #pragma unroll
    for (int jj = 0; jj < 8; jj++)
      bB0[kk][jj] = src[(kk * 16 + hk8 + jj) * 65536 + pos0];

  // (2) reduce 8 per-tile partials -> half sums (L2-resident, 262KB/block)
  for (int e = tid; e < 1024; e += 256) {
    const int i = e >> 4, c4 = (e & 15) * 4;
    floatx4 sq = {0.f, 0.f, 0.f, 0.f}, sk = {0.f, 0.f, 0.f, 0.f};
    #pragma unroll
    for (int t = 0; t < 8; t++) {
      sq += *(const floatx4*)&qp[i * 512 + t * 64 + c4];
      sk += *(const floatx4*)&kp[i * 512 + t * 64 + c4];
    }
    #pragma unroll
    for (int p = 0; p < 4; p++) {
      qh[i][c4 + p] = (half_t)sq[p];
      kh[i][c4 + p] = (half_t)sk[p];
    }
  }
  __syncthreads();

  // (3) ar via MFMA16: wave computes rows [16*wave, 16*wave+16) x all 64 j
  {
    floatx4 ac[4];
    const floatx4 z = {0.f, 0.f, 0.f, 0.f};
    #pragma unroll
    for (int nt = 0; nt < 4; nt++) ac[nt] = z;
    #pragma unroll
    for (int kf = 0; kf < 2; kf++) {
      const int koff = kf * 32 + lq * 8;
      const half8 aF = *(const half8*)&qh[wave * 16 + lrow][koff];
      #pragma unroll
      for (int nt = 0; nt < 4; nt++) {
        const half8 bF = *(const half8*)&kh[nt * 16 + lrow][koff];
        ac[nt] = MFMA16(aF, bF, ac[nt]);
      }
    }
    const float scale = 1.f / (1024.f * 1024.f);
    #pragma unroll
    for (int nt = 0; nt < 4; nt++)
      #pragma unroll
      for (int r = 0; r < 4; r++) {
        const float v = ac[nt][r] * scale;
        arL[wave * 16 + lq * 4 + r][nt * 16 + lrow] = (half_t)(v > 0.f ? v : 0.f);
      }
  }
  __syncthreads();

  // A-frags: A[m=i][k=j]
  half8 aA[2][4];
  #pragma unroll
  for (int mt = 0; mt < 2; mt++)
    #pragma unroll
    for (int kk = 0; kk < 4; kk++)
      aA[mt][kk] = *(const half8*)&arL[mt * 32 + ln31][kk * 16 + hk8];

  #pragma unroll
  for (int t32 = 0; t32 < 2; t32++) {
    const int pos = blockIdx.x * 256 + wave * 64 + t32 * 32 + ln31;
    half8 bB[4];
    if (t32 == 0) {
      #pragma unroll
      for (int kk = 0; kk < 4; kk++) bB[kk] = bB0[kk];
    } else {
      #pragma unroll
      for (int kk = 0; kk < 4; kk++)
        #pragma unroll
        for (int jj = 0; jj < 8; jj++)
          bB[kk][jj] = src[(kk * 16 + hk8 + jj) * 65536 + pos];
    }

    floatx16 c0, c1;
    #pragma unroll
    for (int r = 0; r < 16; r++) { c0[r] = 0.f; c1[r] = 0.f; }
    #pragma unroll
    for (int kk = 0; kk < 4; kk++) {
      c0 = MFMA32(aA[0][kk], bB[kk], c0);
      c1 = MFMA32(aA[1][kk], bB[kk], c1);
    }
    const int h4 = (lane >> 5) * 4;
    #pragma unroll
    for (int r = 0; r < 16; r++) {
      const int row = (r & 3) + h4 + 8 * (r >> 2);
      dst[row * 65536 + pos] = (half_t)c0[r];
      dst[(32 + row) * 65536 + pos] = (half_t)c1[r];
    }
  }
}

// ---------------------------------------------------------------- k_attn ----
// Per (window, t-tile of 128): O = relu(Qm Km^T) V over 8 s-chunks of 128.
// v4: grid swapped to (64 windows, 8 t-tiles) so the 8 blocks sharing one
// window's km+vT (256KB, re-read 8x) land on the SAME XCD (w + 64k === w
// mod 8): per-XCD working set 8 windows x 256KB = 2MB < 4MB L2.
__global__ __launch_bounds__(256, 2) void k_attn(const half_t* __restrict__ qm,
                                                 const half_t* __restrict__ km,
                                                 const half_t* __restrict__ vT,
                                                 float* __restrict__ out) {
  __shared__ __align__(16) half_t Vs[64][136];   // [c][s-chunk]
  __shared__ __align__(16) half_t St[128][138];  // [t][s], pad 138
  const int w = blockIdx.x;
  const int t0 = blockIdx.y * 128;
  const int tid = threadIdx.x;
  const int wave = tid >> 6, lane = tid & 63;
  const int ln31 = lane & 31;
  const int hk8 = (lane >> 5) * 8, hk4 = (lane >> 5) * 4;
  const int w32 = wave * 32;
  const int wbase = w * 65536;

  // Q as B-fragments direct from global: B[n=t][k=c]
  half8 bQ[4][4];
  #pragma unroll
  for (int tt = 0; tt < 4; tt++)
    #pragma unroll
    for (int kk = 0; kk < 4; kk++)
      bQ[tt][kk] = *(const half8*)&qm[wbase + (t0 + tt * 32 + ln31) * 64 + kk * 16 + hk8];

  floatx16 oacc[2];
  #pragma unroll
  for (int ct = 0; ct < 2; ct++)
    #pragma unroll
    for (int r = 0; r < 16; r++) oacc[ct][r] = 0.f;

  for (int sc = 0; sc < 8; sc++) {
    const int s0 = sc * 128;
    __syncthreads();  // previous chunk's Vs/St reads done
    for (int idx = tid; idx < 1024; idx += 256) {
      const int c = idx >> 4, so = (idx & 15) * 8;
      *(half8*)&Vs[c][so] = *(const half8*)&vT[wbase + c * 1024 + s0 + so];
    }
    // K A-frags direct from global (each s-row consumed by exactly one wave)
    half8 aK[4];
    #pragma unroll
    for (int kk = 0; kk < 4; kk++)
      aK[kk] = *(const half8*)&km[wbase + (s0 + w32 + ln31) * 64 + kk * 16 + hk8];
    __syncthreads();  // Vs ready

    // S^T[s][t] = sum_c K[s][c] Q[t][c]; wave owns s-rows [w32, w32+32)
    floatx16 sacc[4];
    #pragma unroll
    for (int tt = 0; tt < 4; tt++)
      #pragma unroll
      for (int r = 0; r < 16; r++) sacc[tt][r] = 0.f;
    #pragma unroll
    for (int kk = 0; kk < 4; kk++)
      #pragma unroll
      for (int tt = 0; tt < 4; tt++)
        sacc[tt] = MFMA32(aK[kk], bQ[tt][kk], sacc[tt]);

    // relu -> packed half4 -> St[t][s] (stride 138 halves = 69 words, odd)
    #pragma unroll
    for (int tt = 0; tt < 4; tt++) {
      const int t = tt * 32 + ln31;
      #pragma unroll
      for (int g = 0; g < 4; g++) {
        const int s = w32 + g * 8 + hk4;
        half4 pk;
        #pragma unroll
        for (int p = 0; p < 4; p++) {
          const float v = sacc[tt][g * 4 + p];
          pk[p] = (half_t)(v > 0.f ? v : 0.f);
        }
        *(half4*)&St[t][s] = pk;
      }
    }
    __syncthreads();  // St ready

    // O^T[c][t] += sum_s V^T[c][s] S[s][t]
    #pragma unroll
    for (int kk = 0; kk < 8; kk++) {
      const half8 bS = *(const half8*)&St[w32 + ln31][kk * 16 + hk8];
      #pragma unroll
      for (int ct = 0; ct < 2; ct++) {
        const half8 aV = *(const half8*)&Vs[ct * 32 + ln31][kk * 16 + hk8];
        oacc[ct] = MFMA32(aV, bS, oacc[ct]);
      }
    }
  }

  // Direct store: lane's col t = t0+w32+ln31 (fixed), rows c vary with reg.
  const int ih = w >> 3, iw = w & 7;
  const int obase = ih * 8192 + iw * 32;
  const int tb = ((t0 + w32) >> 5) * 256 + ln31;
  const int h4 = (lane >> 5) * 4;
  #pragma unroll
  for (int ct = 0; ct < 2; ct++) {
    #pragma unroll
    for (int r = 0; r < 16; r++) {
      const int c = ct * 32 + (r & 3) + h4 + 8 * (r >> 2);
      out[c * 65536 + obase + tb] = oacc[ct][r];
    }
  }
}

// ---------------------------------------------------------------- launch ----
extern "C" void kernel_launch(void* const* d_in, const int* in_sizes, int n_in,
                              void* d_out, int out_size, void* d_ws, size_t ws_size,
                              hipStream_t stream) {
  const float* x = (const float*)d_in[0];
  const float* W = (const float*)d_in[1];
  const float* bias = (const float*)d_in[2];
  float* out = (float*)d_out;

  half_t* q = (half_t*)d_ws;
  half_t* k = q + 4194304;
  half_t* vT = k + 4194304;
  half_t* qm = vT + 4194304;
  half_t* km = qm + 4194304;
  float* qp = (float*)(km + 4194304);  // 512*64
  float* kp = qp + 32768;

  k_qkv<<<dim3(8, 64), 256, 0, stream>>>(x, W, bias, q, k, vT, qp, kp);
  k_mix<<<dim3(256, 2), 256, 0, stream>>>(q, k, qp, kp, qm, km);
  k_attn<<<dim3(64, 8), 256, 0, stream>>>(qm, km, vT, out);
}

// Round 3
// 115.789 us; speedup vs baseline: 1.1114x; 1.0711x over previous
//
#include <hip/hip_runtime.h>

typedef _Float16 half_t;
typedef __attribute__((ext_vector_type(8))) _Float16 half8;
typedef __attribute__((ext_vector_type(4))) _Float16 half4;
typedef __attribute__((ext_vector_type(4))) float floatx4;
typedef __attribute__((ext_vector_type(16))) float floatx16;

#define MFMA16(A, B, C) __builtin_amdgcn_mfma_f32_16x16x32_f16((A), (B), (C), 0, 0, 0)
#define MFMA32(A, B, C) __builtin_amdgcn_mfma_f32_32x32x16_f16((A), (B), (C), 0, 0, 0)

// ----------------------------------------------------------------- k_qkv ----
// Per (t-tile tx, window w): qkv = Xw(128x64) @ W^T(64x192) + bias.
// v3: float4 x-loads (4x fewer VMEM instrs); per-channel q/k sums go
// straight to global 64x64 qsum/ksum via atomicAdd (removes the 262KB
// qp/kp partial buffers that k_mix re-read 512x).
__global__ __launch_bounds__(256) void k_qkv(
    const float* __restrict__ x, const float* __restrict__ W,
    const float* __restrict__ bias, half_t* __restrict__ q,
    half_t* __restrict__ k, half_t* __restrict__ vT,
    float* __restrict__ qsum, float* __restrict__ ksum) {
  // union: [Xs 128x72 | Ws 192x72] (46080B)  vs  [S1 128x136 | S2 64x136]
  __shared__ __align__(16) char smem[52736];
  half_t(*Xs)[72] = (half_t(*)[72])smem;              // 18432B
  half_t(*Ws)[72] = (half_t(*)[72])(smem + 18432);    // 27648B
  half_t(*S1)[136] = (half_t(*)[136])smem;            // 34816B (q|k)
  half_t(*S2)[136] = (half_t(*)[136])(smem + 34816);  // 17408B (vT)
  float* qs_l = (float*)(smem + 52224);
  float* ks_l = qs_l + 64;
  const int w = blockIdx.y;
  const int tx = blockIdx.x;
  const int t0 = tx * 128;
  const int ih = w >> 3, iw = w & 7;
  const int xbase = ih * 8192 + iw * 32 + tx * 1024;
  const int tid = threadIdx.x;

  // x loads as float4: tt = (g>>3)*32 + (g&7)*4 within the 128-row tile
  for (int i = tid; i < 2048; i += 256) {
    const int c = i >> 5, g = i & 31;
    const int tt = (g >> 3) * 32 + (g & 7) * 4;
    const floatx4 v =
        *(const floatx4*)&x[c * 65536 + xbase + (g >> 3) * 256 + (g & 7) * 4];
    #pragma unroll
    for (int p = 0; p < 4; p++) Xs[tt + p][c] = (half_t)v[p];
  }
  for (int i = tid; i < 3072; i += 256) {
    const int o = i >> 4, c4 = (i & 15) * 4;
    const floatx4 v = *(const floatx4*)&W[o * 64 + c4];
    half4 hv;
    #pragma unroll
    for (int p = 0; p < 4; p++) hv[p] = (half_t)v[p];
    *(half4*)&Ws[o][c4] = hv;
  }
  if (tid < 64) { qs_l[tid] = 0.f; ks_l[tid] = 0.f; }
  __syncthreads();

  const int wave = tid >> 6, lane = tid & 63;
  const int lrow = lane & 15, lq = lane >> 4;
  const int rbase = (wave >> 1) * 64;
  const int cbase = (wave & 1) * 96;

  floatx4 acc[4][6];
  const floatx4 z = {0.f, 0.f, 0.f, 0.f};
  #pragma unroll
  for (int mt = 0; mt < 4; mt++)
    #pragma unroll
    for (int nt = 0; nt < 6; nt++) acc[mt][nt] = z;

  #pragma unroll
  for (int kf = 0; kf < 2; kf++) {
    const int koff = kf * 32 + lq * 8;
    half8 a[4], b[6];
    #pragma unroll
    for (int mt = 0; mt < 4; mt++)
      a[mt] = *(const half8*)&Xs[rbase + mt * 16 + lrow][koff];
    #pragma unroll
    for (int nt = 0; nt < 6; nt++)
      b[nt] = *(const half8*)&Ws[cbase + nt * 16 + lrow][koff];
    #pragma unroll
    for (int mt = 0; mt < 4; mt++)
      #pragma unroll
      for (int nt = 0; nt < 6; nt++)
        acc[mt][nt] = MFMA16(a[mt], b[nt], acc[mt][nt]);
  }
  __syncthreads();  // Xs/Ws dead; smem becomes S1/S2

  #pragma unroll
  for (int nt = 0; nt < 6; nt++) {
    const int o = cbase + nt * 16 + lrow;
    const float bs = bias[o];
    if (o < 128) {  // q (o<64) or k: stage rows [t][o]
      float s = 0.f;
      #pragma unroll
      for (int mt = 0; mt < 4; mt++) {
        const int tr = rbase + mt * 16 + lq * 4;
        #pragma unroll
        for (int r = 0; r < 4; r++) {
          const float v = acc[mt][nt][r] + bs;
          S1[tr + r][o] = (half_t)v;
          s += v;
        }
      }
      if (o < 64) atomicAdd(&qs_l[o], s);
      else atomicAdd(&ks_l[o - 64], s);
    } else {  // v: stage transposed [oc][t]
      const int oc = o - 128;
      #pragma unroll
      for (int mt = 0; mt < 4; mt++) {
        const int tr = rbase + mt * 16 + lq * 4;
        half4 pk;
        #pragma unroll
        for (int r = 0; r < 4; r++) pk[r] = (half_t)(acc[mt][nt][r] + bs);
        *(half4*)&S2[oc][tr] = pk;
      }
    }
  }
  __syncthreads();

  // coalesced wide stores
  for (int idx = tid; idx < 3072; idx += 256) {
    if (idx < 2048) {
      const int t = idx >> 4, seg = idx & 15;
      const half8 v = *(const half8*)&S1[t][seg * 8];
      if (seg < 8)
        *(half8*)&q[w * 65536 + (t0 + t) * 64 + seg * 8] = v;
      else
        *(half8*)&k[w * 65536 + (t0 + t) * 64 + (seg - 8) * 8] = v;
    } else {
      const int i2 = idx - 2048;
      const int oc = i2 >> 4, seg = i2 & 15;
      *(half8*)&vT[w * 65536 + oc * 1024 + t0 + seg * 8] =
          *(const half8*)&S2[oc][seg * 8];
    }
  }
  if (tid < 64) {
    atomicAdd(&qsum[w * 64 + tid], qs_l[tid]);
    atomicAdd(&ksum[w * 64 + tid], ks_l[tid]);
  }
}

// ----------------------------------------------------------------- k_mix ----
// Prologue: load 64x64 qsum/ksum (32KB, L2-hot) -> fp16 in LDS; ar =
// relu(qs.ks^T)*2^-20 via 8x MFMA16. Main GEMM: D[i][pos] = sum_j
// ar[i][j]*src[j][pos], M=64, K=64(windows), N=65536.
__global__ __launch_bounds__(256) void k_mix(const half_t* __restrict__ q,
                                             const half_t* __restrict__ k,
                                             const float* __restrict__ qsum,
                                             const float* __restrict__ ksum,
                                             half_t* __restrict__ qm,
                                             half_t* __restrict__ km) {
  __shared__ __align__(16) half_t qh[64][72];
  __shared__ __align__(16) half_t kh[64][72];
  __shared__ __align__(16) half_t arL[64][72];
  const half_t* __restrict__ src = blockIdx.y ? k : q;
  half_t* __restrict__ dst = blockIdx.y ? km : qm;
  const int tid = threadIdx.x;
  const int wave = tid >> 6, lane = tid & 63;
  const int ln31 = lane & 31;
  const int hk8 = (lane >> 5) * 8;
  const int lrow = lane & 15, lq = lane >> 4;

  // t32=0 B-frags issued first: latency hides under the ar prologue
  const int pos0 = blockIdx.x * 256 + wave * 64 + ln31;
  half8 bB0[4];
  #pragma unroll
  for (int kk = 0; kk < 4; kk++)
    #pragma unroll
    for (int jj = 0; jj < 8; jj++)
      bB0[kk][jj] = src[(kk * 16 + hk8 + jj) * 65536 + pos0];

  for (int e = tid; e < 1024; e += 256) {
    const int i = e >> 4, c4 = (e & 15) * 4;
    const floatx4 sq = *(const floatx4*)&qsum[i * 64 + c4];
    const floatx4 sk = *(const floatx4*)&ksum[i * 64 + c4];
    #pragma unroll
    for (int p = 0; p < 4; p++) {
      qh[i][c4 + p] = (half_t)sq[p];
      kh[i][c4 + p] = (half_t)sk[p];
    }
  }
  __syncthreads();

  {  // ar via MFMA16: wave computes rows [16*wave, 16*wave+16) x all 64 j
    floatx4 ac[4];
    const floatx4 z = {0.f, 0.f, 0.f, 0.f};
    #pragma unroll
    for (int nt = 0; nt < 4; nt++) ac[nt] = z;
    #pragma unroll
    for (int kf = 0; kf < 2; kf++) {
      const int koff = kf * 32 + lq * 8;
      const half8 aF = *(const half8*)&qh[wave * 16 + lrow][koff];
      #pragma unroll
      for (int nt = 0; nt < 4; nt++) {
        const half8 bF = *(const half8*)&kh[nt * 16 + lrow][koff];
        ac[nt] = MFMA16(aF, bF, ac[nt]);
      }
    }
    const float scale = 1.f / (1024.f * 1024.f);
    #pragma unroll
    for (int nt = 0; nt < 4; nt++)
      #pragma unroll
      for (int r = 0; r < 4; r++) {
        const float v = ac[nt][r] * scale;
        arL[wave * 16 + lq * 4 + r][nt * 16 + lrow] =
            (half_t)(v > 0.f ? v : 0.f);
      }
  }
  __syncthreads();

  half8 aA[2][4];
  #pragma unroll
  for (int mt = 0; mt < 2; mt++)
    #pragma unroll
    for (int kk = 0; kk < 4; kk++)
      aA[mt][kk] = *(const half8*)&arL[mt * 32 + ln31][kk * 16 + hk8];

  #pragma unroll
  for (int t32 = 0; t32 < 2; t32++) {
    const int pos = blockIdx.x * 256 + wave * 64 + t32 * 32 + ln31;
    half8 bB[4];
    if (t32 == 0) {
      #pragma unroll
      for (int kk = 0; kk < 4; kk++) bB[kk] = bB0[kk];
    } else {
      #pragma unroll
      for (int kk = 0; kk < 4; kk++)
        #pragma unroll
        for (int jj = 0; jj < 8; jj++)
          bB[kk][jj] = src[(kk * 16 + hk8 + jj) * 65536 + pos];
    }

    floatx16 c0, c1;
    #pragma unroll
    for (int r = 0; r < 16; r++) { c0[r] = 0.f; c1[r] = 0.f; }
    #pragma unroll
    for (int kk = 0; kk < 4; kk++) {
      c0 = MFMA32(aA[0][kk], bB[kk], c0);
      c1 = MFMA32(aA[1][kk], bB[kk], c1);
    }
    const int h4 = (lane >> 5) * 4;
    #pragma unroll
    for (int r = 0; r < 16; r++) {
      const int row = (r & 3) + h4 + 8 * (r >> 2);
      dst[row * 65536 + pos] = (half_t)c0[r];
      dst[(32 + row) * 65536 + pos] = (half_t)c1[r];
    }
  }
}

// ---------------------------------------------------------------- k_attn ----
// Per (window, t-tile of 128): O = relu(Qm Km^T) V over 8 s-chunks of 128.
// v5: 2 barriers/chunk (was 3) -- all LDS writes (Vs from prefetched regs +
// St) clustered between one barrier pair; K/V frags for chunk sc+1
// register-prefetched under PV (T14); s_setprio around MFMA clusters (T5).
// Grid (64,8): window -> XCD w mod 8, km/vT re-reads stay L2-local.
__global__ __launch_bounds__(256, 2) void k_attn(const half_t* __restrict__ qm,
                                                 const half_t* __restrict__ km,
                                                 const half_t* __restrict__ vT,
                                                 float* __restrict__ out) {
  __shared__ __align__(16) half_t Vs[64][136];   // [c][s-chunk]
  __shared__ __align__(16) half_t St[128][138];  // [t][s], pad 138
  const int w = blockIdx.x;
  const int t0 = blockIdx.y * 128;
  const int tid = threadIdx.x;
  const int wave = tid >> 6, lane = tid & 63;
  const int ln31 = lane & 31;
  const int hk8 = (lane >> 5) * 8, hk4 = (lane >> 5) * 4;
  const int w32 = wave * 32;
  const int wbase = w * 65536;

  // Q as B-fragments direct from global: B[n=t][k=c]
  half8 bQ[4][4];
  #pragma unroll
  for (int tt = 0; tt < 4; tt++)
    #pragma unroll
    for (int kk = 0; kk < 4; kk++)
      bQ[tt][kk] = *(const half8*)&qm[wbase + (t0 + tt * 32 + ln31) * 64 +
                                      kk * 16 + hk8];

  floatx16 oacc[2];
  #pragma unroll
  for (int ct = 0; ct < 2; ct++)
    #pragma unroll
    for (int r = 0; r < 16; r++) oacc[ct][r] = 0.f;

  // preload chunk 0: V-tile to regs, K A-frags to regs
  half8 vpre[4], aK[4];
  #pragma unroll
  for (int j = 0; j < 4; j++) {
    const int idx = j * 256 + tid;
    const int c = idx >> 4, so = (idx & 15) * 8;
    vpre[j] = *(const half8*)&vT[wbase + c * 1024 + so];
  }
  #pragma unroll
  for (int kk = 0; kk < 4; kk++)
    aK[kk] = *(const half8*)&km[wbase + (w32 + ln31) * 64 + kk * 16 + hk8];

  for (int sc = 0; sc < 8; sc++) {
    // S^T[s][t] = sum_c K[s][c] Q[t][c]; wave owns s-rows [w32, w32+32)
    floatx16 sacc[4];
    #pragma unroll
    for (int tt = 0; tt < 4; tt++)
      #pragma unroll
      for (int r = 0; r < 16; r++) sacc[tt][r] = 0.f;
    __builtin_amdgcn_s_setprio(1);
    #pragma unroll
    for (int kk = 0; kk < 4; kk++)
      #pragma unroll
      for (int tt = 0; tt < 4; tt++)
        sacc[tt] = MFMA32(aK[kk], bQ[tt][kk], sacc[tt]);
    __builtin_amdgcn_s_setprio(0);

    __syncthreads();  // prev chunk's PV done reading Vs/St

    // all LDS writes clustered: Vs from prefetched regs, St = relu(sacc)
    #pragma unroll
    for (int j = 0; j < 4; j++) {
      const int idx = j * 256 + tid;
      const int c = idx >> 4, so = (idx & 15) * 8;
      *(half8*)&Vs[c][so] = vpre[j];
    }
    #pragma unroll
    for (int tt = 0; tt < 4; tt++) {
      const int t = tt * 32 + ln31;
      #pragma unroll
      for (int g = 0; g < 4; g++) {
        const int s = w32 + g * 8 + hk4;
        half4 pk;
        #pragma unroll
        for (int p = 0; p < 4; p++) {
          const float v = sacc[tt][g * 4 + p];
          pk[p] = (half_t)(v > 0.f ? v : 0.f);
        }
        *(half4*)&St[t][s] = pk;
      }
    }
    // issue next chunk's V+K loads; latency hides under PV
    half8 aKn[4];
    if (sc < 7) {
      const int s0n = (sc + 1) * 128;
      #pragma unroll
      for (int j = 0; j < 4; j++) {
        const int idx = j * 256 + tid;
        const int c = idx >> 4, so = (idx & 15) * 8;
        vpre[j] = *(const half8*)&vT[wbase + c * 1024 + s0n + so];
      }
      #pragma unroll
      for (int kk = 0; kk < 4; kk++)
        aKn[kk] = *(const half8*)&km[wbase + (s0n + w32 + ln31) * 64 +
                                     kk * 16 + hk8];
    }
    __syncthreads();  // Vs/St ready

    // O^T[c][t] += sum_s V^T[c][s] S[s][t]
    __builtin_amdgcn_s_setprio(1);
    #pragma unroll
    for (int kk = 0; kk < 8; kk++) {
      const half8 bS = *(const half8*)&St[w32 + ln31][kk * 16 + hk8];
      #pragma unroll
      for (int ct = 0; ct < 2; ct++) {
        const half8 aV = *(const half8*)&Vs[ct * 32 + ln31][kk * 16 + hk8];
        oacc[ct] = MFMA32(aV, bS, oacc[ct]);
      }
    }
    __builtin_amdgcn_s_setprio(0);
    if (sc < 7) {
      #pragma unroll
      for (int kk = 0; kk < 4; kk++) aK[kk] = aKn[kk];
    }
  }

  // Direct store: lane's col t = t0+w32+ln31 (fixed), rows c vary with reg.
  const int ih = w >> 3, iw = w & 7;
  const int obase = ih * 8192 + iw * 32;
  const int tb = ((t0 + w32) >> 5) * 256 + ln31;
  const int h4 = (lane >> 5) * 4;
  #pragma unroll
  for (int ct = 0; ct < 2; ct++) {
    #pragma unroll
    for (int r = 0; r < 16; r++) {
      const int c = ct * 32 + (r & 3) + h4 + 8 * (r >> 2);
      out[c * 65536 + obase + tb] = oacc[ct][r];
    }
  }
}

// ---------------------------------------------------------------- launch ----
extern "C" void kernel_launch(void* const* d_in, const int* in_sizes, int n_in,
                              void* d_out, int out_size, void* d_ws, size_t ws_size,
                              hipStream_t stream) {
  const float* x = (const float*)d_in[0];
  const float* W = (const float*)d_in[1];
  const float* bias = (const float*)d_in[2];
  float* out = (float*)d_out;

  half_t* q = (half_t*)d_ws;
  half_t* k = q + 4194304;
  half_t* vT = k + 4194304;
  half_t* qm = vT + 4194304;
  half_t* km = qm + 4194304;
  float* qsum = (float*)(km + 4194304);  // 64*64
  float* ksum = qsum + 4096;

  hipMemsetAsync(qsum, 0, 2 * 4096 * sizeof(float), stream);
  k_qkv<<<dim3(8, 64), 256, 0, stream>>>(x, W, bias, q, k, vT, qsum, ksum);
  k_mix<<<dim3(256, 2), 256, 0, stream>>>(q, k, qsum, ksum, qm, km);
  k_attn<<<dim3(64, 8), 256, 0, stream>>>(qm, km, vT, out);
}